// Round 5
// baseline (215.095 us; speedup 1.0000x reference)
//
#include <hip/hip_runtime.h>

// ---------------------------------------------------------------------------
// QuantumQKGenerator, fully fused (R8): out[b] = expectations of
// S = QFT * U_circuit * normalize(x[b]).  One wave per row, amps in regs.
//
// R7 post-mortem: kernel correct but VALU-bound (VALUBusy 66%, HBM 2%,
// occupancy 28%, 108us).  This round is an instruction diet + occupancy fix
// with IDENTICAL math/structure:
//   - intra-FFT twiddles: compile-time pi/8-step tables (were 32 sincos)
//   - cross-FFT twiddles: per-stage recurrence w *= W, W = literal
//     constants (were 96 sincos); premultiply-exchange butterfly
//     (v' = mybit ? w*c : c; f = shfl(v'); res = f + sel*v')
//   - CNOT-ring+bitrev permutation is GF(2)-LINEAR: m(l*16+i) =
//     m(l<<4) ^ m(i), m(i) constant-folds (was a 30-op chain x16)
//   - LDS scratch in fp16 (RNE pack): 4KB/wave not 8KB -> ~17KB/block,
//     + __launch_bounds__(256,5) -> 5-6 waves/SIMD (was LDS/VGPR-capped 4)
// ---------------------------------------------------------------------------

typedef _Float16 half2_t __attribute__((ext_vector_type(2)));

__device__ __forceinline__ unsigned pk16(float a, float b) {
    half2_t h; h[0] = (_Float16)a; h[1] = (_Float16)b;    // RNE v_cvt_f16_f32
    return __builtin_bit_cast(unsigned, h);
}
__device__ __forceinline__ float2 up16(unsigned u) {
    half2_t h = __builtin_bit_cast(half2_t, u);
    return make_float2((float)h[0], (float)h[1]);
}

// 6-stage full-wave butterfly sum (all 64 lanes end with the total).
__device__ __forceinline__ float wred(float v) {
    v += __shfl_xor(v, 1);
    v += __shfl_xor(v, 2);
    v += __shfl_xor(v, 4);
    v += __shfl_xor(v, 8);
    v += __shfl_xor(v, 16);
    v += __shfl_xor(v, 32);
    return v;
}

// CNOT-ring + bit-reversal permutation (R5/R7-verified composition).
// Linear over GF(2): cnotrev(a ^ b) = cnotrev(a) ^ cnotrev(b).
__device__ __forceinline__ int cnotrev(int k) {
    int m = (int)(__brev((unsigned)k) >> 22);
    #pragma unroll
    for (int q = 9; q >= 0; --q) {
        const int pc = (q == 9) ? 0 : 9 - q;
        const int pt = (q == 9) ? 9 : 8 - q;
        m ^= ((m >> pc) & 1) << pt;
    }
    return m;
}

__global__ __launch_bounds__(256, 5) void fused_kernel(const float* __restrict__ w,
                                                       const float* __restrict__ x,
                                                       float* __restrict__ out)
{
    __shared__ float uu[10][8];                    // combined Mz*My*Mx per wire
    __shared__ float ryc[10], rys[10];             // layer-3 RY coefficients
    __shared__ __align__(16) unsigned scr[4][1024];// per-wave fp16 scratch (4KB)
    const int tid = threadIdx.x;
    const int wv = tid >> 6, l = tid & 63;
    const int row = blockIdx.x * 4 + wv;
    unsigned* bw = scr[wv];

    // ---- per-block setup: combined single-qubit unitaries (uniform) ----
    if (tid < 10) {
        float t0 = w[tid*4 + 0] * 0.5f, t1 = w[tid*4 + 1] * 0.5f;
        float t2 = w[tid*4 + 2] * 0.5f, t3 = w[tid*4 + 3] * 0.5f;
        float s0, c0, s1, c1, s2, c2, s3, c3;
        __sincosf(t0, &s0, &c0);
        __sincosf(t1, &s1, &c1);
        __sincosf(t2, &s2, &c2);
        __sincosf(t3, &s3, &c3);
        // M = Mz*My*Mx (RX applied first) -- R7-verified.
        uu[tid][0] =  c2*c1*c0 + s2*s1*s0;     // u00r
        uu[tid][1] =  c2*s1*s0 - s2*c1*c0;     // u00i
        uu[tid][2] = -(c2*s1*c0 + s2*c1*s0);   // u01r
        uu[tid][3] =  s2*s1*c0 - c2*c1*s0;     // u01i
        uu[tid][4] =  c2*s1*c0 + s2*c1*s0;     // u10r
        uu[tid][5] =  s2*s1*c0 - c2*c1*s0;     // u10i
        uu[tid][6] =  c2*c1*c0 + s2*s1*s0;     // u11r =  u00r
        uu[tid][7] =  s2*c1*c0 - c2*s1*s0;     // u11i = -u00i
        ryc[tid] = c3;
        rys[tid] = s3;
    }
    __syncthreads();

    // ---- load row, normalize (1/||x|| * 1/32 folded into one scale) ----
    const float* xr = x + (size_t)row * 1024 + l * 16;
    float4 v0 = ((const float4*)xr)[0];
    float4 v1 = ((const float4*)xr)[1];
    float4 v2 = ((const float4*)xr)[2];
    float4 v3 = ((const float4*)xr)[3];
    float ss = v0.x*v0.x + v0.y*v0.y + v0.z*v0.z + v0.w*v0.w
             + v1.x*v1.x + v1.y*v1.y + v1.z*v1.z + v1.w*v1.w
             + v2.x*v2.x + v2.y*v2.y + v2.z*v2.z + v2.w*v2.w
             + v3.x*v3.x + v3.y*v3.y + v3.z*v3.z + v3.w*v3.w;
    ss = wred(ss);
    const float scale = 0.03125f / fmaxf(sqrtf(ss), 1e-8f);

    float2 c[16];
    c[0]  = make_float2(v0.x*scale, 0.f); c[1]  = make_float2(v0.y*scale, 0.f);
    c[2]  = make_float2(v0.z*scale, 0.f); c[3]  = make_float2(v0.w*scale, 0.f);
    c[4]  = make_float2(v1.x*scale, 0.f); c[5]  = make_float2(v1.y*scale, 0.f);
    c[6]  = make_float2(v1.z*scale, 0.f); c[7]  = make_float2(v1.w*scale, 0.f);
    c[8]  = make_float2(v2.x*scale, 0.f); c[9]  = make_float2(v2.y*scale, 0.f);
    c[10] = make_float2(v2.z*scale, 0.f); c[11] = make_float2(v2.w*scale, 0.f);
    c[12] = make_float2(v3.x*scale, 0.f); c[13] = make_float2(v3.y*scale, 0.f);
    c[14] = make_float2(v3.z*scale, 0.f); c[15] = make_float2(v3.w*scale, 0.f);

    // ---- combined RX/RY/RZ layers: bit p <-> wire 9-p (R7-verified) ----
    #pragma unroll
    for (int p = 0; p < 4; ++p) {
        const float* U = uu[9 - p];
        const float u00r = U[0], u00i = U[1], u01r = U[2], u01i = U[3];
        const float u10r = U[4], u10i = U[5], u11r = U[6], u11i = U[7];
        const int m = 1 << p;
        #pragma unroll
        for (int i = 0; i < 16; ++i) {
            if (i & m) continue;
            const int j = i | m;
            const float ar = c[i].x, ai = c[i].y, br = c[j].x, bi = c[j].y;
            c[i].x = u00r*ar - u00i*ai + u01r*br - u01i*bi;
            c[i].y = u00r*ai + u00i*ar + u01r*bi + u01i*br;
            c[j].x = u10r*ar - u10i*ai + u11r*br - u11i*bi;
            c[j].y = u10r*ai + u10i*ar + u11r*bi + u11i*br;
        }
    }
    #pragma unroll
    for (int e = 0; e < 6; ++e) {
        const float* U = uu[5 - e];
        const int mybit = (l >> e) & 1;
        const float car = mybit ? U[6] : U[0];
        const float cai = mybit ? U[7] : U[1];
        const float cbr = mybit ? U[4] : U[2];
        const float cbi = mybit ? U[5] : U[3];
        #pragma unroll
        for (int i = 0; i < 16; ++i) {
            const float fr = __shfl_xor(c[i].x, 1 << e);
            const float fi = __shfl_xor(c[i].y, 1 << e);
            const float ar = c[i].x, ai = c[i].y;
            c[i].x = car*ar - cai*ai + cbr*fr - cbi*fi;
            c[i].y = car*ai + cai*ar + cbr*fi + cbi*fr;
        }
    }

    // ---- CNOT ring + bit-reversal: wave-local fp16 LDS gather ----
    #pragma unroll
    for (int j = 0; j < 8; ++j) {
        const int su = l*8 + (j ^ (l & 7));
        uint2 pv;
        pv.x = pk16(c[2*j].x,     c[2*j].y);
        pv.y = pk16(c[2*j + 1].x, c[2*j + 1].y);
        ((uint2*)bw)[su] = pv;
    }
    const int mb = cnotrev(l << 4);
    #pragma unroll
    for (int i = 0; i < 16; ++i) {
        const int m = mb ^ cnotrev(i);          // cnotrev(i) constant-folds
        const int lm = m >> 4, um = (m >> 1) & 7, lo = m & 1;
        const unsigned v = bw[(lm*8 + (um ^ (lm & 7)))*2 + lo];
        c[i] = up16(v);
    }

    // ---- layer-3 RY on REVERSED bits: bit p <-> wire p (R7-verified) ----
    #pragma unroll
    for (int p = 0; p < 4; ++p) {
        const float cc = ryc[p], sv = rys[p];
        const int m = 1 << p;
        #pragma unroll
        for (int i = 0; i < 16; ++i) {
            if (i & m) continue;
            const int j = i | m;
            const float ar = c[i].x, ai = c[i].y, br = c[j].x, bi = c[j].y;
            c[i].x = cc*ar - sv*br;  c[i].y = cc*ai - sv*bi;
            c[j].x = sv*ar + cc*br;  c[j].y = sv*ai + cc*bi;
        }
    }
    #pragma unroll
    for (int e = 0; e < 6; ++e) {
        const float cc = ryc[4 + e], sv = rys[4 + e];
        const int mybit = (l >> e) & 1;
        const float sel = mybit ? sv : -sv;
        #pragma unroll
        for (int i = 0; i < 16; ++i) {
            const float fr = __shfl_xor(c[i].x, 1 << e);
            const float fi = __shfl_xor(c[i].y, 1 << e);
            c[i].x = cc*c[i].x + sel*fr;
            c[i].y = cc*c[i].y + sel*fi;
        }
    }

    // ---- 1024-pt DIT FFT (bit-reversed input, positive twiddles) ----
    // intra-lane stages 1..4: compile-time pi/8-step twiddle tables
    {
        const float TC8[8] = { 1.f,  0.92387953f,  0.70710678f,  0.38268343f,
                               0.f, -0.38268343f, -0.70710678f, -0.92387953f };
        const float TS8[8] = { 0.f,  0.38268343f,  0.70710678f,  0.92387953f,
                               1.f,  0.92387953f,  0.70710678f,  0.38268343f };
        #pragma unroll
        for (int st = 1; st <= 4; ++st) {
            const int hf = 1 << (st - 1);
            #pragma unroll
            for (int i = 0; i < 16; ++i) {
                if (i & hf) continue;
                const int j = i | hf;
                const int tix = (i & (hf - 1)) << (4 - st);
                const float cwv = TC8[tix], swv = TS8[tix];
                const float tr = cwv*c[j].x - swv*c[j].y;
                const float ti = cwv*c[j].y + swv*c[j].x;
                const float ur = c[i].x, ui = c[i].y;
                c[i].x = ur + tr; c[i].y = ui + ti;
                c[j].x = ur - tr; c[j].y = ui - ti;
            }
        }
    }
    // cross-lane stages 5..10 (lane-bit e2, st = 5+e2):
    //   w(i) = w_base * W^i via recurrence; premultiply-exchange butterfly.
    {
        // W = e^{i*2pi/2^st}
        const float WC[6] = { 0.98078528f, 0.99518473f, 0.99879546f,
                              0.99969882f, 0.99992470f, 0.99998118f };
        const float WS[6] = { 0.19509032f, 0.09801714f, 0.04906767f,
                              0.02454123f, 0.01227154f, 0.00613588f };
        #pragma unroll
        for (int e2 = 0; e2 < 6; ++e2) {
            const int st = 5 + e2;
            const float astep = 6.28318530717958647f / (float)(1 << st);
            const int mybit = (l >> e2) & 1;
            const float sel = mybit ? -1.f : 1.f;
            const float cW = WC[e2], sW = WS[e2];
            float cb, sb;
            __sincosf(astep * 16.0f * (float)(l & ((1 << e2) - 1)), &sb, &cb);
            float cw = cb, sw = sb;
            #pragma unroll
            for (int i = 0; i < 16; ++i) {
                const float pr = cw*c[i].x - sw*c[i].y;     // w * own
                const float pi = cw*c[i].y + sw*c[i].x;
                const float vr = mybit ? pr : c[i].x;       // b-lane sends w*b
                const float vi = mybit ? pi : c[i].y;
                const float fr = __shfl_xor(vr, 1 << e2);
                const float fi = __shfl_xor(vi, 1 << e2);
                c[i].x = fmaf(sel, vr, fr);                 // a: a+w*b, b: a-w*b
                c[i].y = fmaf(sel, vi, fi);
                const float ncw = cw*cW - sw*sW;            // w *= W
                sw = sw*cW + cw*sW;
                cw = ncw;
            }
        }
    }

    // ---- expectations (R7-verified structure; fp16 staged partners) ----
    #pragma unroll
    for (int j = 0; j < 8; ++j) {
        const int su = l*8 + (j ^ (l & 7));
        uint2 pv;
        pv.x = pk16(c[2*j].x,     c[2*j].y);
        pv.y = pk16(c[2*j + 1].x, c[2*j + 1].y);
        ((uint2*)bw)[su] = pv;
    }

    float P2s = 0.f;
    #pragma unroll
    for (int i = 0; i < 16; ++i)
        P2s += c[i].x*c[i].x + c[i].y*c[i].y;

    float outv = 0.f;   // lane o ends up holding out[row][o]

    // intra-lane qubits: k-bit p = 0..3 -> q = 9-p
    #pragma unroll
    for (int p = 0; p < 4; ++p) {
        const int m = 1 << p;
        const int q = 9 - p;
        float rr = 0.f, ii = 0.f, zz = 0.f;
        #pragma unroll
        for (int i = 0; i < 16; ++i) {
            if (i & m) continue;
            const int j = i | m;
            rr += c[i].x*c[j].x + c[i].y*c[j].y;
            ii += c[i].x*c[j].y - c[i].y*c[j].x;
            zz += (c[i].x*c[i].x + c[i].y*c[i].y) - (c[j].x*c[j].x + c[j].y*c[j].y);
        }
        rr = wred(rr);
        ii = wred(ii);
        zz = wred(zz);
        outv = (l == q)      ? 2.f*rr : outv;
        outv = (l == 10 + q) ? 2.f*ii : outv;
        outv = (l == 20 + q) ? zz     : outv;
    }

    // cross-lane qubits: lane-bit e (k-bit 4+e) -> q = 5-e
    #pragma unroll
    for (int e = 0; e < 6; ++e) {
        const int q = 5 - e;
        const int part = l ^ (1 << e);
        const int mybit = (l >> e) & 1;
        const float sgn = mybit ? -1.f : 1.f;
        const int j0 = mybit ? 4 : 0;   // my half of the pair's units (LDS addr only)
        float rr = 0.f, ii = 0.f;
        #pragma unroll
        for (int j = 0; j < 4; ++j) {
            const int su = part*8 + ((j0 + j) ^ (part & 7));
            const uint2 d = ((const uint2*)bw)[su];
            const float2 f01 = up16(d.x);   // partner complex 0 (re, im)
            const float2 f23 = up16(d.y);   // partner complex 1 (re, im)
            const float2 a0 = c[2*j],     a1 = c[2*j + 1];
            const float2 b0 = c[2*j + 8], b1 = c[2*j + 9];
            const float m0x = mybit ? b0.x : a0.x;
            const float m0y = mybit ? b0.y : a0.y;
            const float m1x = mybit ? b1.x : a1.x;
            const float m1y = mybit ? b1.y : a1.y;
            rr += m0x*f01.x + m0y*f01.y;
            ii += m0x*f01.y - m0y*f01.x;
            rr += m1x*f23.x + m1y*f23.y;
            ii += m1x*f23.y - m1y*f23.x;
        }
        const float rr_s = wred(rr);
        const float ii_s = wred(sgn * ii);
        const float zz_s = wred(sgn * P2s);
        outv = (l == q)      ? 2.f*rr_s : outv;
        outv = (l == 10 + q) ? 2.f*ii_s : outv;
        outv = (l == 20 + q) ? zz_s     : outv;
    }

    if (l < 30)
        out[(size_t)row * 30 + l] = outv;
}

// ---------------------------------------------------------------------------
extern "C" void kernel_launch(void* const* d_in, const int* in_sizes, int n_in,
                              void* d_out, int out_size, void* d_ws, size_t ws_size,
                              hipStream_t stream) {
    const float* x = (const float*)d_in[0];   // [8192][1024]
    const float* w = (const float*)d_in[1];   // [10][4]
    float* out = (float*)d_out;               // [8192][30]
    (void)d_ws; (void)ws_size;                // workspace not needed

    fused_kernel<<<2048, 256, 0, stream>>>(w, x, out);
}

// Round 6
// 157.758 us; speedup vs baseline: 1.3635x; 1.3635x over previous
//
#include <hip/hip_runtime.h>

// ---------------------------------------------------------------------------
// QuantumQKGenerator, fully fused (R9): out[b] = expectations of
// S = QFT * U_circuit * normalize(x[b]).  One wave per row, amps in regs.
//
// R8 post-mortem: __launch_bounds__(256,5) forced the 8-wave/SIMD occupancy
// tier (VGPR budget 64 -- tiers quantize at 64/128/256), compiler allocated
// 48 and spilled ~170B/thread -> 346 MB scratch writes, 160us.  LESSON: a
// min-waves request above the tier the live state fits in = silent
// catastrophic spill.  R9 = R8's verified instruction diet (twiddle tables,
// w*=W recurrence, GF(2)-linear cnotrev, premultiply-exchange butterfly)
// with __launch_bounds__(256,4) (128-VGPR tier, 4 waves/SIMD; R7 needed
// only 76 VGPR) and R7's fp32 float4 LDS staging (33KB/block still fits
// 4 blocks/CU at this tier; better absmax + fewer bank conflicts).
// ---------------------------------------------------------------------------

// 6-stage full-wave butterfly sum (all 64 lanes end with the total).
__device__ __forceinline__ float wred(float v) {
    v += __shfl_xor(v, 1);
    v += __shfl_xor(v, 2);
    v += __shfl_xor(v, 4);
    v += __shfl_xor(v, 8);
    v += __shfl_xor(v, 16);
    v += __shfl_xor(v, 32);
    return v;
}

// CNOT-ring + bit-reversal permutation (R5/R7-verified composition).
// Linear over GF(2): cnotrev(a ^ b) = cnotrev(a) ^ cnotrev(b).
__device__ __forceinline__ int cnotrev(int k) {
    int m = (int)(__brev((unsigned)k) >> 22);
    #pragma unroll
    for (int q = 9; q >= 0; --q) {
        const int pc = (q == 9) ? 0 : 9 - q;
        const int pt = (q == 9) ? 9 : 8 - q;
        m ^= ((m >> pc) & 1) << pt;
    }
    return m;
}

__global__ __launch_bounds__(256, 4) void fused_kernel(const float* __restrict__ w,
                                                       const float* __restrict__ x,
                                                       float* __restrict__ out)
{
    __shared__ float uu[10][8];                    // combined Mz*My*Mx per wire
    __shared__ float ryc[10], rys[10];             // layer-3 RY coefficients
    __shared__ __align__(16) float scr[4][2048];   // per-wave fp32 scratch (8KB)
    const int tid = threadIdx.x;
    const int wv = tid >> 6, l = tid & 63;
    const int row = blockIdx.x * 4 + wv;
    float* bw = scr[wv];

    // ---- per-block setup: combined single-qubit unitaries (uniform) ----
    if (tid < 10) {
        float t0 = w[tid*4 + 0] * 0.5f, t1 = w[tid*4 + 1] * 0.5f;
        float t2 = w[tid*4 + 2] * 0.5f, t3 = w[tid*4 + 3] * 0.5f;
        float s0, c0, s1, c1, s2, c2, s3, c3;
        __sincosf(t0, &s0, &c0);
        __sincosf(t1, &s1, &c1);
        __sincosf(t2, &s2, &c2);
        __sincosf(t3, &s3, &c3);
        // M = Mz*My*Mx (RX applied first) -- R7-verified.
        uu[tid][0] =  c2*c1*c0 + s2*s1*s0;     // u00r
        uu[tid][1] =  c2*s1*s0 - s2*c1*c0;     // u00i
        uu[tid][2] = -(c2*s1*c0 + s2*c1*s0);   // u01r
        uu[tid][3] =  s2*s1*c0 - c2*c1*s0;     // u01i
        uu[tid][4] =  c2*s1*c0 + s2*c1*s0;     // u10r
        uu[tid][5] =  s2*s1*c0 - c2*c1*s0;     // u10i
        uu[tid][6] =  c2*c1*c0 + s2*s1*s0;     // u11r =  u00r
        uu[tid][7] =  s2*c1*c0 - c2*s1*s0;     // u11i = -u00i
        ryc[tid] = c3;
        rys[tid] = s3;
    }
    __syncthreads();

    // ---- load row, normalize (1/||x|| * 1/32 folded into one scale) ----
    const float* xr = x + (size_t)row * 1024 + l * 16;
    float4 v0 = ((const float4*)xr)[0];
    float4 v1 = ((const float4*)xr)[1];
    float4 v2 = ((const float4*)xr)[2];
    float4 v3 = ((const float4*)xr)[3];
    float ss = v0.x*v0.x + v0.y*v0.y + v0.z*v0.z + v0.w*v0.w
             + v1.x*v1.x + v1.y*v1.y + v1.z*v1.z + v1.w*v1.w
             + v2.x*v2.x + v2.y*v2.y + v2.z*v2.z + v2.w*v2.w
             + v3.x*v3.x + v3.y*v3.y + v3.z*v3.z + v3.w*v3.w;
    ss = wred(ss);
    const float scale = 0.03125f / fmaxf(sqrtf(ss), 1e-8f);

    float2 c[16];
    c[0]  = make_float2(v0.x*scale, 0.f); c[1]  = make_float2(v0.y*scale, 0.f);
    c[2]  = make_float2(v0.z*scale, 0.f); c[3]  = make_float2(v0.w*scale, 0.f);
    c[4]  = make_float2(v1.x*scale, 0.f); c[5]  = make_float2(v1.y*scale, 0.f);
    c[6]  = make_float2(v1.z*scale, 0.f); c[7]  = make_float2(v1.w*scale, 0.f);
    c[8]  = make_float2(v2.x*scale, 0.f); c[9]  = make_float2(v2.y*scale, 0.f);
    c[10] = make_float2(v2.z*scale, 0.f); c[11] = make_float2(v2.w*scale, 0.f);
    c[12] = make_float2(v3.x*scale, 0.f); c[13] = make_float2(v3.y*scale, 0.f);
    c[14] = make_float2(v3.z*scale, 0.f); c[15] = make_float2(v3.w*scale, 0.f);

    // ---- combined RX/RY/RZ layers: bit p <-> wire 9-p (R7-verified) ----
    #pragma unroll
    for (int p = 0; p < 4; ++p) {
        const float* U = uu[9 - p];
        const float u00r = U[0], u00i = U[1], u01r = U[2], u01i = U[3];
        const float u10r = U[4], u10i = U[5], u11r = U[6], u11i = U[7];
        const int m = 1 << p;
        #pragma unroll
        for (int i = 0; i < 16; ++i) {
            if (i & m) continue;
            const int j = i | m;
            const float ar = c[i].x, ai = c[i].y, br = c[j].x, bi = c[j].y;
            c[i].x = u00r*ar - u00i*ai + u01r*br - u01i*bi;
            c[i].y = u00r*ai + u00i*ar + u01r*bi + u01i*br;
            c[j].x = u10r*ar - u10i*ai + u11r*br - u11i*bi;
            c[j].y = u10r*ai + u10i*ar + u11r*bi + u11i*br;
        }
    }
    #pragma unroll
    for (int e = 0; e < 6; ++e) {
        const float* U = uu[5 - e];
        const int mybit = (l >> e) & 1;
        const float car = mybit ? U[6] : U[0];
        const float cai = mybit ? U[7] : U[1];
        const float cbr = mybit ? U[4] : U[2];
        const float cbi = mybit ? U[5] : U[3];
        #pragma unroll
        for (int i = 0; i < 16; ++i) {
            const float fr = __shfl_xor(c[i].x, 1 << e);
            const float fi = __shfl_xor(c[i].y, 1 << e);
            const float ar = c[i].x, ai = c[i].y;
            c[i].x = car*ar - cai*ai + cbr*fr - cbi*fi;
            c[i].y = car*ai + cai*ar + cbr*fi + cbi*fr;
        }
    }

    // ---- CNOT ring + bit-reversal: wave-local fp32 LDS gather ----
    #pragma unroll
    for (int j = 0; j < 8; ++j) {
        const int su = l*8 + (j ^ (l & 7));
        ((float4*)bw)[su] = make_float4(c[2*j].x, c[2*j].y, c[2*j+1].x, c[2*j+1].y);
    }
    const int mb = cnotrev(l << 4);
    #pragma unroll
    for (int i = 0; i < 16; ++i) {
        const int m = mb ^ cnotrev(i);          // cnotrev(i) constant-folds
        const int lm = m >> 4, um = (m >> 1) & 7, lo = m & 1;
        const int su = lm*8 + (um ^ (lm & 7));
        c[i] = ((const float2*)bw)[su*2 + lo];
    }

    // ---- layer-3 RY on REVERSED bits: bit p <-> wire p (R7-verified) ----
    #pragma unroll
    for (int p = 0; p < 4; ++p) {
        const float cc = ryc[p], sv = rys[p];
        const int m = 1 << p;
        #pragma unroll
        for (int i = 0; i < 16; ++i) {
            if (i & m) continue;
            const int j = i | m;
            const float ar = c[i].x, ai = c[i].y, br = c[j].x, bi = c[j].y;
            c[i].x = cc*ar - sv*br;  c[i].y = cc*ai - sv*bi;
            c[j].x = sv*ar + cc*br;  c[j].y = sv*ai + cc*bi;
        }
    }
    #pragma unroll
    for (int e = 0; e < 6; ++e) {
        const float cc = ryc[4 + e], sv = rys[4 + e];
        const int mybit = (l >> e) & 1;
        const float sel = mybit ? sv : -sv;
        #pragma unroll
        for (int i = 0; i < 16; ++i) {
            const float fr = __shfl_xor(c[i].x, 1 << e);
            const float fi = __shfl_xor(c[i].y, 1 << e);
            c[i].x = cc*c[i].x + sel*fr;
            c[i].y = cc*c[i].y + sel*fi;
        }
    }

    // ---- 1024-pt DIT FFT (bit-reversed input, positive twiddles) ----
    // intra-lane stages 1..4: compile-time pi/8-step twiddle tables
    {
        const float TC8[8] = { 1.f,  0.92387953f,  0.70710678f,  0.38268343f,
                               0.f, -0.38268343f, -0.70710678f, -0.92387953f };
        const float TS8[8] = { 0.f,  0.38268343f,  0.70710678f,  0.92387953f,
                               1.f,  0.92387953f,  0.70710678f,  0.38268343f };
        #pragma unroll
        for (int st = 1; st <= 4; ++st) {
            const int hf = 1 << (st - 1);
            #pragma unroll
            for (int i = 0; i < 16; ++i) {
                if (i & hf) continue;
                const int j = i | hf;
                const int tix = (i & (hf - 1)) << (4 - st);
                const float cwv = TC8[tix], swv = TS8[tix];
                const float tr = cwv*c[j].x - swv*c[j].y;
                const float ti = cwv*c[j].y + swv*c[j].x;
                const float ur = c[i].x, ui = c[i].y;
                c[i].x = ur + tr; c[i].y = ui + ti;
                c[j].x = ur - tr; c[j].y = ui - ti;
            }
        }
    }
    // cross-lane stages 5..10 (lane-bit e2, st = 5+e2):
    //   w(i) = w_base * W^i via recurrence; premultiply-exchange butterfly.
    {
        // W = e^{i*2pi/2^st}
        const float WC[6] = { 0.98078528f, 0.99518473f, 0.99879546f,
                              0.99969882f, 0.99992470f, 0.99998118f };
        const float WS[6] = { 0.19509032f, 0.09801714f, 0.04906767f,
                              0.02454123f, 0.01227154f, 0.00613588f };
        #pragma unroll
        for (int e2 = 0; e2 < 6; ++e2) {
            const int st = 5 + e2;
            const float astep = 6.28318530717958647f / (float)(1 << st);
            const int mybit = (l >> e2) & 1;
            const float sel = mybit ? -1.f : 1.f;
            const float cW = WC[e2], sW = WS[e2];
            float cb, sb;
            __sincosf(astep * 16.0f * (float)(l & ((1 << e2) - 1)), &sb, &cb);
            float cw = cb, sw = sb;
            #pragma unroll
            for (int i = 0; i < 16; ++i) {
                const float pr = cw*c[i].x - sw*c[i].y;     // w * own
                const float pi = cw*c[i].y + sw*c[i].x;
                const float vr = mybit ? pr : c[i].x;       // b-lane sends w*b
                const float vi = mybit ? pi : c[i].y;
                const float fr = __shfl_xor(vr, 1 << e2);
                const float fi = __shfl_xor(vi, 1 << e2);
                c[i].x = fmaf(sel, vr, fr);                 // a: a+w*b, b: a-w*b
                c[i].y = fmaf(sel, vi, fi);
                const float ncw = cw*cW - sw*sW;            // w *= W
                sw = sw*cW + cw*sW;
                cw = ncw;
            }
        }
    }

    // ---- expectations (R7-verified structure, fp32 staged partners) ----
    #pragma unroll
    for (int j = 0; j < 8; ++j) {
        const int su = l*8 + (j ^ (l & 7));
        ((float4*)bw)[su] = make_float4(c[2*j].x, c[2*j].y, c[2*j+1].x, c[2*j+1].y);
    }

    float P2s = 0.f;
    #pragma unroll
    for (int i = 0; i < 16; ++i)
        P2s += c[i].x*c[i].x + c[i].y*c[i].y;

    float outv = 0.f;   // lane o ends up holding out[row][o]

    // intra-lane qubits: k-bit p = 0..3 -> q = 9-p
    #pragma unroll
    for (int p = 0; p < 4; ++p) {
        const int m = 1 << p;
        const int q = 9 - p;
        float rr = 0.f, ii = 0.f, zz = 0.f;
        #pragma unroll
        for (int i = 0; i < 16; ++i) {
            if (i & m) continue;
            const int j = i | m;
            rr += c[i].x*c[j].x + c[i].y*c[j].y;
            ii += c[i].x*c[j].y - c[i].y*c[j].x;
            zz += (c[i].x*c[i].x + c[i].y*c[i].y) - (c[j].x*c[j].x + c[j].y*c[j].y);
        }
        rr = wred(rr);
        ii = wred(ii);
        zz = wred(zz);
        outv = (l == q)      ? 2.f*rr : outv;
        outv = (l == 10 + q) ? 2.f*ii : outv;
        outv = (l == 20 + q) ? zz     : outv;
    }

    // cross-lane qubits: lane-bit e (k-bit 4+e) -> q = 5-e
    #pragma unroll
    for (int e = 0; e < 6; ++e) {
        const int q = 5 - e;
        const int part = l ^ (1 << e);
        const int mybit = (l >> e) & 1;
        const float sgn = mybit ? -1.f : 1.f;
        const int j0 = mybit ? 4 : 0;   // my half of the pair's units (LDS addr only)
        float rr = 0.f, ii = 0.f;
        #pragma unroll
        for (int j = 0; j < 4; ++j) {
            const int su = part*8 + ((j0 + j) ^ (part & 7));
            const float4 f = ((const float4*)bw)[su];
            const float2 a0 = c[2*j],     a1 = c[2*j + 1];
            const float2 b0 = c[2*j + 8], b1 = c[2*j + 9];
            const float m0x = mybit ? b0.x : a0.x;
            const float m0y = mybit ? b0.y : a0.y;
            const float m1x = mybit ? b1.x : a1.x;
            const float m1y = mybit ? b1.y : a1.y;
            rr += m0x*f.x + m0y*f.y;
            ii += m0x*f.y - m0y*f.x;
            rr += m1x*f.z + m1y*f.w;
            ii += m1x*f.w - m1y*f.z;
        }
        const float rr_s = wred(rr);
        const float ii_s = wred(sgn * ii);
        const float zz_s = wred(sgn * P2s);
        outv = (l == q)      ? 2.f*rr_s : outv;
        outv = (l == 10 + q) ? 2.f*ii_s : outv;
        outv = (l == 20 + q) ? zz_s     : outv;
    }

    if (l < 30)
        out[(size_t)row * 30 + l] = outv;
}

// ---------------------------------------------------------------------------
extern "C" void kernel_launch(void* const* d_in, const int* in_sizes, int n_in,
                              void* d_out, int out_size, void* d_ws, size_t ws_size,
                              hipStream_t stream) {
    const float* x = (const float*)d_in[0];   // [8192][1024]
    const float* w = (const float*)d_in[1];   // [10][4]
    float* out = (float*)d_out;               // [8192][30]
    (void)d_ws; (void)ws_size;                // workspace not needed

    fused_kernel<<<2048, 256, 0, stream>>>(w, x, out);
}

// Round 7
// 154.012 us; speedup vs baseline: 1.3966x; 1.0243x over previous
//
#include <hip/hip_runtime.h>

// ---------------------------------------------------------------------------
// QuantumQKGenerator, fully fused (R10): out[b] = expectations of
// S = QFT * U_circuit * normalize(x[b]).  One wave per row, amps in regs.
//
// R9 post-mortem: __launch_bounds__(256,4) STILL clamped the allocator to
// 64 VGPR -> 43 MB scratch writes.  Cross-round evidence:
//   (256)   -> VGPR 76, WRITE 0.96 MB, no spill   (R7)
//   (256,4) -> VGPR 64, WRITE 43 MB spill         (R9)
//   (256,5) -> VGPR 48, WRITE 346 MB spill        (R8)
// LESSON (toolchain-empirical): ANY min-waves 2nd arg makes the allocator
// clamp to the max-occupancy tier and silently spill; the nominal
// 512/waves budget arithmetic is NOT what it implements.  Omit the arg.
//
// R10 = R9's verified instruction diet (compile-time twiddle tables, w*=W
// recurrence, GF(2)-linear cnotrev, premultiply-exchange butterfly, fused
// Mz*My*Mx layers) + plain __launch_bounds__(256) + fp32 LDS staging.
// ---------------------------------------------------------------------------

// 6-stage full-wave butterfly sum (all 64 lanes end with the total).
__device__ __forceinline__ float wred(float v) {
    v += __shfl_xor(v, 1);
    v += __shfl_xor(v, 2);
    v += __shfl_xor(v, 4);
    v += __shfl_xor(v, 8);
    v += __shfl_xor(v, 16);
    v += __shfl_xor(v, 32);
    return v;
}

// CNOT-ring + bit-reversal permutation (R5/R7-verified composition).
// Linear over GF(2): cnotrev(a ^ b) = cnotrev(a) ^ cnotrev(b).
__device__ __forceinline__ int cnotrev(int k) {
    int m = (int)(__brev((unsigned)k) >> 22);
    #pragma unroll
    for (int q = 9; q >= 0; --q) {
        const int pc = (q == 9) ? 0 : 9 - q;
        const int pt = (q == 9) ? 9 : 8 - q;
        m ^= ((m >> pc) & 1) << pt;
    }
    return m;
}

__global__ __launch_bounds__(256) void fused_kernel(const float* __restrict__ w,
                                                    const float* __restrict__ x,
                                                    float* __restrict__ out)
{
    __shared__ float uu[10][8];                    // combined Mz*My*Mx per wire
    __shared__ float ryc[10], rys[10];             // layer-3 RY coefficients
    __shared__ __align__(16) float scr[4][2048];   // per-wave fp32 scratch (8KB)
    const int tid = threadIdx.x;
    const int wv = tid >> 6, l = tid & 63;
    const int row = blockIdx.x * 4 + wv;
    float* bw = scr[wv];

    // ---- per-block setup: combined single-qubit unitaries (uniform) ----
    if (tid < 10) {
        float t0 = w[tid*4 + 0] * 0.5f, t1 = w[tid*4 + 1] * 0.5f;
        float t2 = w[tid*4 + 2] * 0.5f, t3 = w[tid*4 + 3] * 0.5f;
        float s0, c0, s1, c1, s2, c2, s3, c3;
        __sincosf(t0, &s0, &c0);
        __sincosf(t1, &s1, &c1);
        __sincosf(t2, &s2, &c2);
        __sincosf(t3, &s3, &c3);
        // M = Mz*My*Mx (RX applied first) -- R7-verified.
        uu[tid][0] =  c2*c1*c0 + s2*s1*s0;     // u00r
        uu[tid][1] =  c2*s1*s0 - s2*c1*c0;     // u00i
        uu[tid][2] = -(c2*s1*c0 + s2*c1*s0);   // u01r
        uu[tid][3] =  s2*s1*c0 - c2*c1*s0;     // u01i
        uu[tid][4] =  c2*s1*c0 + s2*c1*s0;     // u10r
        uu[tid][5] =  s2*s1*c0 - c2*c1*s0;     // u10i
        uu[tid][6] =  c2*c1*c0 + s2*s1*s0;     // u11r =  u00r
        uu[tid][7] =  s2*c1*c0 - c2*s1*s0;     // u11i = -u00i
        ryc[tid] = c3;
        rys[tid] = s3;
    }
    __syncthreads();

    // ---- load row, normalize (1/||x|| * 1/32 folded into one scale) ----
    const float* xr = x + (size_t)row * 1024 + l * 16;
    float4 v0 = ((const float4*)xr)[0];
    float4 v1 = ((const float4*)xr)[1];
    float4 v2 = ((const float4*)xr)[2];
    float4 v3 = ((const float4*)xr)[3];
    float ss = v0.x*v0.x + v0.y*v0.y + v0.z*v0.z + v0.w*v0.w
             + v1.x*v1.x + v1.y*v1.y + v1.z*v1.z + v1.w*v1.w
             + v2.x*v2.x + v2.y*v2.y + v2.z*v2.z + v2.w*v2.w
             + v3.x*v3.x + v3.y*v3.y + v3.z*v3.z + v3.w*v3.w;
    ss = wred(ss);
    const float scale = 0.03125f / fmaxf(sqrtf(ss), 1e-8f);

    float2 c[16];
    c[0]  = make_float2(v0.x*scale, 0.f); c[1]  = make_float2(v0.y*scale, 0.f);
    c[2]  = make_float2(v0.z*scale, 0.f); c[3]  = make_float2(v0.w*scale, 0.f);
    c[4]  = make_float2(v1.x*scale, 0.f); c[5]  = make_float2(v1.y*scale, 0.f);
    c[6]  = make_float2(v1.z*scale, 0.f); c[7]  = make_float2(v1.w*scale, 0.f);
    c[8]  = make_float2(v2.x*scale, 0.f); c[9]  = make_float2(v2.y*scale, 0.f);
    c[10] = make_float2(v2.z*scale, 0.f); c[11] = make_float2(v2.w*scale, 0.f);
    c[12] = make_float2(v3.x*scale, 0.f); c[13] = make_float2(v3.y*scale, 0.f);
    c[14] = make_float2(v3.z*scale, 0.f); c[15] = make_float2(v3.w*scale, 0.f);

    // ---- combined RX/RY/RZ layers: bit p <-> wire 9-p (R7-verified) ----
    #pragma unroll
    for (int p = 0; p < 4; ++p) {
        const float* U = uu[9 - p];
        const float u00r = U[0], u00i = U[1], u01r = U[2], u01i = U[3];
        const float u10r = U[4], u10i = U[5], u11r = U[6], u11i = U[7];
        const int m = 1 << p;
        #pragma unroll
        for (int i = 0; i < 16; ++i) {
            if (i & m) continue;
            const int j = i | m;
            const float ar = c[i].x, ai = c[i].y, br = c[j].x, bi = c[j].y;
            c[i].x = u00r*ar - u00i*ai + u01r*br - u01i*bi;
            c[i].y = u00r*ai + u00i*ar + u01r*bi + u01i*br;
            c[j].x = u10r*ar - u10i*ai + u11r*br - u11i*bi;
            c[j].y = u10r*ai + u10i*ar + u11r*bi + u11i*br;
        }
    }
    #pragma unroll
    for (int e = 0; e < 6; ++e) {
        const float* U = uu[5 - e];
        const int mybit = (l >> e) & 1;
        const float car = mybit ? U[6] : U[0];
        const float cai = mybit ? U[7] : U[1];
        const float cbr = mybit ? U[4] : U[2];
        const float cbi = mybit ? U[5] : U[3];
        #pragma unroll
        for (int i = 0; i < 16; ++i) {
            const float fr = __shfl_xor(c[i].x, 1 << e);
            const float fi = __shfl_xor(c[i].y, 1 << e);
            const float ar = c[i].x, ai = c[i].y;
            c[i].x = car*ar - cai*ai + cbr*fr - cbi*fi;
            c[i].y = car*ai + cai*ar + cbr*fi + cbi*fr;
        }
    }

    // ---- CNOT ring + bit-reversal: wave-local fp32 LDS gather ----
    #pragma unroll
    for (int j = 0; j < 8; ++j) {
        const int su = l*8 + (j ^ (l & 7));
        ((float4*)bw)[su] = make_float4(c[2*j].x, c[2*j].y, c[2*j+1].x, c[2*j+1].y);
    }
    const int mb = cnotrev(l << 4);
    #pragma unroll
    for (int i = 0; i < 16; ++i) {
        const int m = mb ^ cnotrev(i);          // cnotrev(i) constant-folds
        const int lm = m >> 4, um = (m >> 1) & 7, lo = m & 1;
        const int su = lm*8 + (um ^ (lm & 7));
        c[i] = ((const float2*)bw)[su*2 + lo];
    }

    // ---- layer-3 RY on REVERSED bits: bit p <-> wire p (R7-verified) ----
    #pragma unroll
    for (int p = 0; p < 4; ++p) {
        const float cc = ryc[p], sv = rys[p];
        const int m = 1 << p;
        #pragma unroll
        for (int i = 0; i < 16; ++i) {
            if (i & m) continue;
            const int j = i | m;
            const float ar = c[i].x, ai = c[i].y, br = c[j].x, bi = c[j].y;
            c[i].x = cc*ar - sv*br;  c[i].y = cc*ai - sv*bi;
            c[j].x = sv*ar + cc*br;  c[j].y = sv*ai + cc*bi;
        }
    }
    #pragma unroll
    for (int e = 0; e < 6; ++e) {
        const float cc = ryc[4 + e], sv = rys[4 + e];
        const int mybit = (l >> e) & 1;
        const float sel = mybit ? sv : -sv;
        #pragma unroll
        for (int i = 0; i < 16; ++i) {
            const float fr = __shfl_xor(c[i].x, 1 << e);
            const float fi = __shfl_xor(c[i].y, 1 << e);
            c[i].x = cc*c[i].x + sel*fr;
            c[i].y = cc*c[i].y + sel*fi;
        }
    }

    // ---- 1024-pt DIT FFT (bit-reversed input, positive twiddles) ----
    // intra-lane stages 1..4: compile-time pi/8-step twiddle tables
    {
        const float TC8[8] = { 1.f,  0.92387953f,  0.70710678f,  0.38268343f,
                               0.f, -0.38268343f, -0.70710678f, -0.92387953f };
        const float TS8[8] = { 0.f,  0.38268343f,  0.70710678f,  0.92387953f,
                               1.f,  0.92387953f,  0.70710678f,  0.38268343f };
        #pragma unroll
        for (int st = 1; st <= 4; ++st) {
            const int hf = 1 << (st - 1);
            #pragma unroll
            for (int i = 0; i < 16; ++i) {
                if (i & hf) continue;
                const int j = i | hf;
                const int tix = (i & (hf - 1)) << (4 - st);
                const float cwv = TC8[tix], swv = TS8[tix];
                const float tr = cwv*c[j].x - swv*c[j].y;
                const float ti = cwv*c[j].y + swv*c[j].x;
                const float ur = c[i].x, ui = c[i].y;
                c[i].x = ur + tr; c[i].y = ui + ti;
                c[j].x = ur - tr; c[j].y = ui - ti;
            }
        }
    }
    // cross-lane stages 5..10 (lane-bit e2, st = 5+e2):
    //   w(i) = w_base * W^i via recurrence; premultiply-exchange butterfly.
    {
        // W = e^{i*2pi/2^st}
        const float WC[6] = { 0.98078528f, 0.99518473f, 0.99879546f,
                              0.99969882f, 0.99992470f, 0.99998118f };
        const float WS[6] = { 0.19509032f, 0.09801714f, 0.04906767f,
                              0.02454123f, 0.01227154f, 0.00613588f };
        #pragma unroll
        for (int e2 = 0; e2 < 6; ++e2) {
            const int st = 5 + e2;
            const float astep = 6.28318530717958647f / (float)(1 << st);
            const int mybit = (l >> e2) & 1;
            const float sel = mybit ? -1.f : 1.f;
            const float cW = WC[e2], sW = WS[e2];
            float cb, sb;
            __sincosf(astep * 16.0f * (float)(l & ((1 << e2) - 1)), &sb, &cb);
            float cw = cb, sw = sb;
            #pragma unroll
            for (int i = 0; i < 16; ++i) {
                const float pr = cw*c[i].x - sw*c[i].y;     // w * own
                const float pi = cw*c[i].y + sw*c[i].x;
                const float vr = mybit ? pr : c[i].x;       // b-lane sends w*b
                const float vi = mybit ? pi : c[i].y;
                const float fr = __shfl_xor(vr, 1 << e2);
                const float fi = __shfl_xor(vi, 1 << e2);
                c[i].x = fmaf(sel, vr, fr);                 // a: a+w*b, b: a-w*b
                c[i].y = fmaf(sel, vi, fi);
                const float ncw = cw*cW - sw*sW;            // w *= W
                sw = sw*cW + cw*sW;
                cw = ncw;
            }
        }
    }

    // ---- expectations (R7-verified structure, fp32 staged partners) ----
    #pragma unroll
    for (int j = 0; j < 8; ++j) {
        const int su = l*8 + (j ^ (l & 7));
        ((float4*)bw)[su] = make_float4(c[2*j].x, c[2*j].y, c[2*j+1].x, c[2*j+1].y);
    }

    float P2s = 0.f;
    #pragma unroll
    for (int i = 0; i < 16; ++i)
        P2s += c[i].x*c[i].x + c[i].y*c[i].y;

    float outv = 0.f;   // lane o ends up holding out[row][o]

    // intra-lane qubits: k-bit p = 0..3 -> q = 9-p
    #pragma unroll
    for (int p = 0; p < 4; ++p) {
        const int m = 1 << p;
        const int q = 9 - p;
        float rr = 0.f, ii = 0.f, zz = 0.f;
        #pragma unroll
        for (int i = 0; i < 16; ++i) {
            if (i & m) continue;
            const int j = i | m;
            rr += c[i].x*c[j].x + c[i].y*c[j].y;
            ii += c[i].x*c[j].y - c[i].y*c[j].x;
            zz += (c[i].x*c[i].x + c[i].y*c[i].y) - (c[j].x*c[j].x + c[j].y*c[j].y);
        }
        rr = wred(rr);
        ii = wred(ii);
        zz = wred(zz);
        outv = (l == q)      ? 2.f*rr : outv;
        outv = (l == 10 + q) ? 2.f*ii : outv;
        outv = (l == 20 + q) ? zz     : outv;
    }

    // cross-lane qubits: lane-bit e (k-bit 4+e) -> q = 5-e
    #pragma unroll
    for (int e = 0; e < 6; ++e) {
        const int q = 5 - e;
        const int part = l ^ (1 << e);
        const int mybit = (l >> e) & 1;
        const float sgn = mybit ? -1.f : 1.f;
        const int j0 = mybit ? 4 : 0;   // my half of the pair's units (LDS addr only)
        float rr = 0.f, ii = 0.f;
        #pragma unroll
        for (int j = 0; j < 4; ++j) {
            const int su = part*8 + ((j0 + j) ^ (part & 7));
            const float4 f = ((const float4*)bw)[su];
            const float2 a0 = c[2*j],     a1 = c[2*j + 1];
            const float2 b0 = c[2*j + 8], b1 = c[2*j + 9];
            const float m0x = mybit ? b0.x : a0.x;
            const float m0y = mybit ? b0.y : a0.y;
            const float m1x = mybit ? b1.x : a1.x;
            const float m1y = mybit ? b1.y : a1.y;
            rr += m0x*f.x + m0y*f.y;
            ii += m0x*f.y - m0y*f.x;
            rr += m1x*f.z + m1y*f.w;
            ii += m1x*f.w - m1y*f.z;
        }
        const float rr_s = wred(rr);
        const float ii_s = wred(sgn * ii);
        const float zz_s = wred(sgn * P2s);
        outv = (l == q)      ? 2.f*rr_s : outv;
        outv = (l == 10 + q) ? 2.f*ii_s : outv;
        outv = (l == 20 + q) ? zz_s     : outv;
    }

    if (l < 30)
        out[(size_t)row * 30 + l] = outv;
}

// ---------------------------------------------------------------------------
extern "C" void kernel_launch(void* const* d_in, const int* in_sizes, int n_in,
                              void* d_out, int out_size, void* d_ws, size_t ws_size,
                              hipStream_t stream) {
    const float* x = (const float*)d_in[0];   // [8192][1024]
    const float* w = (const float*)d_in[1];   // [10][4]
    float* out = (float*)d_out;               // [8192][30]
    (void)d_ws; (void)ws_size;                // workspace not needed

    fused_kernel<<<2048, 256, 0, stream>>>(w, x, out);
}